// Round 10
// baseline (449.605 us; speedup 1.0000x reference)
//
#include <hip/hip_runtime.h>

// TALayer: deformable 1D conv, fixed integer taps d[j] ∈ {-17,-16,-15,-1,0,1,15,16,17}
// out[b,o,t] = sum_{c,j} W[o,c,j] * x[b,c,t+d[j]] (zero-pad OOB) + bias[o]
// B=8, C=O=64, T=65536. bf16 MFMA GEMM: C[64, B*T] = W[64,576] * Xg[576, B*T].
// R7: (256,3) + K-loop 1-chunk pipeline + XCD swizzle: 197->133us.
// R8 FAILED: NT=256 persistent pipeline spilled (v[19]+nt4 acc > 128-reg cap).
// R9: NT=128, 4 waves, nt=2, (256,4): 108us. occ 35%, MfmaUtil 14.5%, 23% HBM.
// R10 FAILED: 2-wave blocks: 116us, occ 27% (scheduler didn't pack more blocks),
//     cover-ratio not binding. Reverted to R9 geometry.
// R14: hide stage latency under K-loop WITHOUT R8's spill (R9's small state fits):
//     - double-buffered xs (2x22.8KB = 45.7KB -> 3 blocks/CU by LDS)
//     - per tile: issue(it+1) -> K-loop(cur) -> commit(it+1 -> nxt) -> direct
//       stores -> ONE barrier -> swap. Stage HBM latency hides under MFMA phase.
//     - epilogue os round-trip deleted: direct stores (16-lane x 4B = 64B segs,
//       XCD-local adjacent blocks -> full lines in L2). Bias added in-reg.
//     - live across K-loop: v[11]=44 + frags 48 + acc 32 AGPR ~ 150 < 170 cap.
//     Tripwires: FETCH >> 80MB = spill; WRITE > 1.3x output = store amplification.

typedef short bf16x8 __attribute__((ext_vector_type(8)));   // 8 bf16 (4 VGPRs)
typedef short bf16x4 __attribute__((ext_vector_type(4)));   // 4 bf16 (8 B, ds_read_b64)
typedef float f32x4  __attribute__((ext_vector_type(4)));   // MFMA accumulator / 16B vec

#define T_LEN   65536
#define NT      128           // t-tile per iteration
#define NTILE   4             // tiles per block
#define SPAN    (NT * NTILE)  // 512 t per block
#define ROWS    168           // staged rows: global t in [t0-20, t0+148)
#define PITCH   68            // shorts per LDS row (136 B)
#define LOFF    20            // x[t] -> LDS row (t - t0 + 20)
#define NCHUNK  18            // K = 576 = 18 * 32
#define XS_SHORTS (ROWS * PITCH)        // 11,424 shorts = 22,848 B per buffer

__device__ __forceinline__ short f2bf(float f) {
    union { float f; unsigned u; } v; v.f = f;
    unsigned u = v.u;
    u += 0x7fffu + ((u >> 16) & 1u);   // round-to-nearest-even
    return (short)(u >> 16);
}

// Weight -> MFMA A-fragment order (bf16), layout [ch][mt][lane][8]:
// W2[((ch*4 + mt)*64 + lane)*8 + i] = bf16(W[o = mt*16 + (lane&15)][kk = ch*32 + (lane>>4)*8 + i])
// kk = j*64 + c -> j = kk>>6, c = kk&63;  W strides [o][c][j] = (576, 9, 1).
__global__ void prep_w_kernel(const float* __restrict__ w, short* __restrict__ W2) {
    int idx = blockIdx.x * 256 + threadIdx.x;       // 0 .. 4607
    if (idx >= 4 * NCHUNK * 64) return;
    int lane = idx & 63;
    int g    = idx >> 6;            // ch*4 + mt
    int ch   = g >> 2;
    int mt   = g & 3;
    int o    = mt * 16 + (lane & 15);
    bf16x8 v;
#pragma unroll
    for (int i = 0; i < 8; ++i) {
        int kk = ch * 32 + (lane >> 4) * 8 + i;
        int j = kk >> 6, c = kk & 63;
        v[i] = f2bf(w[o * 576 + c * 9 + j]);
    }
    *(bf16x8*)(W2 + (size_t)idx * 8) = v;
}

__global__ __launch_bounds__(256, 3)
void ta_main_kernel(const float* __restrict__ x, const short* __restrict__ W2,
                    const float* __restrict__ bias, float* __restrict__ out) {
    __shared__ __align__(16) short xsbuf[2][XS_SHORTS];   // double-buffered staging

    const int tid  = threadIdx.x;
    const int wv   = tid >> 6;                      // wave -> t-quarter (32 t each)
    const int lane = tid & 63;
    const int l15  = lane & 15;
    const int quad = lane >> 4;
    const int b    = blockIdx.y;
    // XCD swizzle: gridDim.x = 128 ≡ 0 mod 8 -> bijective. XCD k owns 16
    // consecutive bx (8192 consecutive t): halo L2 reuse + contiguous writes.
    const int bxd  = blockIdx.x;                    // 0..127
    const int bx   = (bxd & 7) * 16 + (bxd >> 3);
    const int tg0  = bx * SPAN;

    // ---- staging machinery: 256 threads, c = tid>>2, q = tid&3, f = q+4i < 42 ----
    const int c = tid >> 2;
    const int q = tid & 3;
    const float* xrow = x + (((size_t)(b * 64 + c)) << 16);

    f32x4 v[11];                                    // staged tile in flight (44 VGPR)

    auto issue = [&](const int t0) {
        const int tbase = t0 - LOFF;
        if ((t0 >= LOFF) && (t0 + (ROWS - LOFF) <= T_LEN)) {
#pragma unroll
            for (int i = 0; i < 11; ++i) {
                const int f = q + 4 * i;
                if (f < 42) v[i] = *(const f32x4*)(xrow + tbase + 4 * f);
            }
        } else {                                    // boundary tiles: clamped scalars
#pragma unroll
            for (int i = 0; i < 11; ++i) {
                const int f = q + 4 * i;
                if (f < 42) {
                    const int tg = tbase + 4 * f;
                    f32x4 t;
                    t[0] = ((unsigned)(tg + 0) < (unsigned)T_LEN) ? xrow[tg + 0] : 0.f;
                    t[1] = ((unsigned)(tg + 1) < (unsigned)T_LEN) ? xrow[tg + 1] : 0.f;
                    t[2] = ((unsigned)(tg + 2) < (unsigned)T_LEN) ? xrow[tg + 2] : 0.f;
                    t[3] = ((unsigned)(tg + 3) < (unsigned)T_LEN) ? xrow[tg + 3] : 0.f;
                    v[i] = t;
                }
            }
        }
    };
    auto commit = [&](short* dst) {                 // cvt + transpose into LDS
#pragma unroll
        for (int i = 0; i < 11; ++i) {
            const int f = q + 4 * i;
            if (f < 42) {
                const int tt = 4 * f;
                dst[(tt + 0) * PITCH + c] = f2bf(v[i][0]);
                dst[(tt + 1) * PITCH + c] = f2bf(v[i][1]);
                dst[(tt + 2) * PITCH + c] = f2bf(v[i][2]);
                dst[(tt + 3) * PITCH + c] = f2bf(v[i][3]);
            }
        }
    };

    // prologue: stage tile 0 into buffer 0
    issue(tg0);
    commit(xsbuf[0]);
    __syncthreads();

    int bbase[2];
#pragma unroll
    for (int nt = 0; nt < 2; ++nt) {
        const int tl = wv * 32 + nt * 16 + l15;
        bbase[nt] = (tl + 3) * PITCH + quad * 8;    // shorts; +3 so roff >= 0
    }
    const short* w2p = W2 + (size_t)lane * 8;
    const size_t outb = ((size_t)(b * 64)) << 16;
    const int dtab[9] = {-17, -16, -15, -1, 0, 1, 15, 16, 17};

    short* cur = xsbuf[0];
    short* nxt = xsbuf[1];

#pragma unroll
    for (int it = 0; it < NTILE; ++it) {
        const int t0 = tg0 + it * NT;
        const bool more = (it + 1 < NTILE);

        // (A) issue next tile's loads -> in flight across the K-loop
        if (more) issue(t0 + NT);
        __builtin_amdgcn_sched_barrier(0);          // don't sink stage loads below

        // (B) K-loop on cur: 18 chunks of 32, 1-chunk W2/B software pipeline
        f32x4 acc[4][2] = {};                       // [mt][nt]
        bf16x8 a_cur[4], b_cur[2], a_nxt[4], b_nxt[2];
        {
            const int roff0 = (dtab[0] + 17) * PITCH + 0;
#pragma unroll
            for (int mt = 0; mt < 4; ++mt)
                a_cur[mt] = *(const bf16x8*)(w2p + (size_t)(0 * 4 + mt) * 512);
#pragma unroll
            for (int nt = 0; nt < 2; ++nt) {
                union { bf16x8 v8; bf16x4 v4[2]; } u;
                u.v4[0] = *(const bf16x4*)(cur + bbase[nt] + roff0);
                u.v4[1] = *(const bf16x4*)(cur + bbase[nt] + roff0 + 4);
                b_cur[nt] = u.v8;
            }
        }
#pragma unroll
        for (int ch = 0; ch < NCHUNK; ++ch) {
            if (ch < NCHUNK - 1) {
                const int chn = ch + 1;
                const int jn = chn >> 1, hn = chn & 1;
                const int roffn = (dtab[jn] + 17) * PITCH + hn * 32;   // compile-time
#pragma unroll
                for (int mt = 0; mt < 4; ++mt)
                    a_nxt[mt] = *(const bf16x8*)(w2p + (size_t)(chn * 4 + mt) * 512);
#pragma unroll
                for (int nt = 0; nt < 2; ++nt) {
                    union { bf16x8 v8; bf16x4 v4[2]; } u;
                    u.v4[0] = *(const bf16x4*)(cur + bbase[nt] + roffn);
                    u.v4[1] = *(const bf16x4*)(cur + bbase[nt] + roffn + 4);
                    b_nxt[nt] = u.v8;
                }
            }
#pragma unroll
            for (int mt = 0; mt < 4; ++mt)
#pragma unroll
                for (int nt = 0; nt < 2; ++nt)
                    acc[mt][nt] = __builtin_amdgcn_mfma_f32_16x16x32_bf16(a_cur[mt], b_cur[nt], acc[mt][nt], 0, 0, 0);
            if (ch < NCHUNK - 1) {
#pragma unroll
                for (int mt = 0; mt < 4; ++mt) a_cur[mt] = a_nxt[mt];
#pragma unroll
                for (int nt = 0; nt < 2; ++nt) b_cur[nt] = b_nxt[nt];
            }
        }

        // (C) commit next tile into nxt (vmcnt wait lands here, after K-loop)
        if (more) commit(nxt);

        // (D) direct epilogue: C/D layout row(m)=quad*4+r, col(n)=l15.
        //     o = mt*16+quad*4+r, t = t0 + wv*32 + nt*16 + l15.
        //     16-lane groups -> 64B contiguous segments; same-XCD neighbors
        //     complete the lines in L2.
        {
            f32x4 bv[4];
#pragma unroll
            for (int mt = 0; mt < 4; ++mt)
                bv[mt] = *(const f32x4*)(bias + mt * 16 + quad * 4);
            float* obase = out + outb + t0 + wv * 32 + l15;
#pragma unroll
            for (int mt = 0; mt < 4; ++mt)
#pragma unroll
                for (int r = 0; r < 4; ++r) {
                    const int orow = (mt * 16 + quad * 4 + r) << 16;
#pragma unroll
                    for (int nt = 0; nt < 2; ++nt)
                        obase[orow + nt * 16] = acc[mt][nt][r] + bv[mt][r];
                }
        }

        __syncthreads();                            // nxt visible; cur free to overwrite
        short* tmp = cur; cur = nxt; nxt = tmp;
    }
}

extern "C" void kernel_launch(void* const* d_in, const int* in_sizes, int n_in,
                              void* d_out, int out_size, void* d_ws, size_t ws_size,
                              hipStream_t stream) {
    const float* x    = (const float*)d_in[0];
    const float* w    = (const float*)d_in[1];
    const float* bias = (const float*)d_in[2];
    float* out = (float*)d_out;
    short* W2  = (short*)d_ws;                      // 4*18*64*8*2 = 73,728 B

    hipLaunchKernelGGL(prep_w_kernel, dim3(18), dim3(256), 0, stream, w, W2);
    hipLaunchKernelGGL(ta_main_kernel, dim3(T_LEN / SPAN, 8), dim3(256), 0, stream,
                       x, W2, bias, out);
}